// Round 20
// baseline (82.930 us; speedup 1.0000x reference)
//
#include <hip/hip_runtime.h>
#include <hip/hip_bf16.h>
#include <stdint.h>
#include <stddef.h>

#define NTOT 8192
#define BS   4096
#define DIM  1024
#define NTRI 2080   // 64*65/2 triangular tiles
#define QS   20.0f  // i8 quant scale: ±127/20 = ±6.35 sigma coverage

// ws layout (bytes)
#define OFF_TB      0u          // i8, tiled layout: 8192*1024 = 8388608
#define OFF_SQ      8388608u    // f32 [8192]
#define OFF_COLPART 8421376u    // f32 [512][1024] per-16-row col partials
#define OFF_COLP2   10518528u   // f32 [8][1024]
#define OFF_BWP     10551296u   // f32 [8]
#define OFF_PART    10551360u   // f32 [NTRI]

// tb tiled layout: element (row, k) at
//   R*16384 + kt*1024 + kq*256 + r15*16 + b
// where R=row>>4, r15=row&15, kt=k>>6, kq=(k>>4)&3, b=k&15.
// KEY: this is exactly MFMA-fragment order. A lane's 32x32x32_i8 operand for
// k-step s (0..31) is the contiguous 16B at
//   (RB + (col5>>4))*16384 + s*512 + hi32*256 + (lane&15)*16
// so the GEMM streams fragments L2->VGPR directly: NO LDS, NO barriers,
// no stage/compute lockstep. Per-wave-load = 4 dense 256B segments.
// A and B share the (lane,byte)->k map -> Gram contraction exact (R14-proven).
// NOTE (R17 lesson): no device-scope fences/atomics — __threadfence on
// non-coherent per-XCD L2s destroyed staging locality (48.5 -> 283us).

typedef __attribute__((ext_vector_type(4)))  int   i32x4;
typedef __attribute__((ext_vector_type(16))) int   i32x16;

__device__ __forceinline__ float fast_sqrt(float x) {
#if __has_builtin(__builtin_amdgcn_sqrtf)
  return __builtin_amdgcn_sqrtf(x);
#else
  float r; asm("v_sqrt_f32 %0, %1" : "=v"(r) : "v"(x)); return r;
#endif
}

__device__ __forceinline__ float fast_exp2(float x) {
#if __has_builtin(__builtin_amdgcn_exp2f)
  return __builtin_amdgcn_exp2f(x);
#else
  float r; asm("v_exp_f32 %0, %1" : "=v"(r) : "v"(x)); return r;
#endif
}

__device__ __forceinline__ int quant4(float4 v) {
  int q0 = __float2int_rn(fminf(fmaxf(v.x * QS, -127.f), 127.f));
  int q1 = __float2int_rn(fminf(fmaxf(v.y * QS, -127.f), 127.f));
  int q2 = __float2int_rn(fminf(fmaxf(v.z * QS, -127.f), 127.f));
  int q3 = __float2int_rn(fminf(fmaxf(v.w * QS, -127.f), 127.f));
  return (q0 & 255) | ((q1 & 255) << 8) | ((q2 & 255) << 16) | ((q3 & 255) << 24);
}

// ---- kernel A: i8 quantize into tiled layout + row sq + col partials ----
__global__ __launch_bounds__(256) void prep_kernel(const float* __restrict__ src,
                                                   const float* __restrict__ tgt,
                                                   unsigned char* __restrict__ tb,
                                                   float* __restrict__ sq,
                                                   float* __restrict__ colpart) {
  const int t = threadIdx.x;
  const int lane = t & 63, wave = t >> 6;
  const int R = blockIdx.x;        // 16-row block
  const int r0 = R * 16;
  const int kt = t >> 4, kq = (t >> 2) & 3, b0 = (t & 3) * 4;
  unsigned char* dstbase = tb + (size_t)R * 16384 + kt * 1024 + kq * 256 + b0;
  __shared__ float rs[16][4];
  float c0 = 0.f, c1 = 0.f, c2 = 0.f, c3 = 0.f;
#pragma unroll 4
  for (int r = 0; r < 16; ++r) {
    const int row = r0 + r;
    const float* base = (row < BS) ? (src + (size_t)row * DIM)
                                   : (tgt + (size_t)(row - BS) * DIM);
    float4 v = *reinterpret_cast<const float4*>(base + t * 4);
    *reinterpret_cast<int*>(dstbase + r * 16) = quant4(v);   // r15 = r
    c0 += v.x; c1 += v.y; c2 += v.z; c3 += v.w;
    float s = v.x*v.x + v.y*v.y + v.z*v.z + v.w*v.w;
#pragma unroll
    for (int off = 32; off > 0; off >>= 1) s += __shfl_down(s, off, 64);
    if (lane == 0) rs[r][wave] = s;
  }
  float4 cp = {c0, c1, c2, c3};
  *reinterpret_cast<float4*>(colpart + (size_t)R * 1024 + t * 4) = cp;
  __syncthreads();
  if (t < 16) sq[r0 + t] = (rs[t][0] + rs[t][1]) + (rs[t][2] + rs[t][3]);
}

// ---- kernel B: reduce 512 col-partial groups -> 8 ----
__global__ __launch_bounds__(1024) void colred_kernel(const float* __restrict__ colpart,
                                                      float* __restrict__ colp2) {
  const int b = blockIdx.x, t = threadIdx.x;   // 8 blocks x 1024 cols
  float s = 0.f;
  for (int g = b * 64; g < b * 64 + 64; ++g) s += colpart[(size_t)g * 1024 + t];
  colp2[b * 1024 + t] = s;
}

// ---- kernel C: bandwidth from analytic sum(L2) ----
__global__ __launch_bounds__(1024) void bw_kernel(const float* __restrict__ sq,
                                                  const float* __restrict__ colp2,
                                                  float* __restrict__ bwp) {
  const int t = threadIdx.x;
  double s1 = 0.0;
#pragma unroll
  for (int i = 0; i < 8; ++i) s1 += (double)sq[t + i * 1024];
  float s = 0.f;
#pragma unroll
  for (int j = 0; j < 8; ++j) s += colp2[j * 1024 + t];
  double s2 = (double)s * (double)s;
  __shared__ double r1[1024], r2[1024];
  r1[t] = s1; r2[t] = s2;
  __syncthreads();
  for (int off = 512; off > 0; off >>= 1) {
    if (t < off) { r1[t] += r1[t + off]; r2[t] += r2[t + off]; }
    __syncthreads();
  }
  if (t == 0) {
    const double n = (double)NTOT;
    double sumL2 = 2.0 * n * r1[0] - 2.0 * r2[0];
    double bw = sumL2 / (n * n - n);
    bw = bw / 4.0;  // KERNEL_MUL^(KERNEL_NUM//2) = 2^2
    const double LOG2E = 1.4426950408889634;
    for (int k = 0; k < 5; ++k)
      bwp[k] = (float)(-LOG2E / (bw * (double)(1 << k)));  // exp2-folded
  }
}

#define MFI8(a, b, c) __builtin_amdgcn_mfma_i32_32x32x32_i8(a, b, c, 0, 0, 0)
#define LDQ(P, off) (*reinterpret_cast<const i32x4*>((P) + (off)))

#define EXP5(x16) ({ float u_ = fast_exp2(x16);                               \
                     float u2_ = u_ * u_, u4_ = u2_ * u2_;                    \
                     float u8_ = u4_ * u4_, u16_ = u8_ * u8_;                 \
                     ((u_ + u2_) + (u4_ + u8_)) + u16_; })

// ---- kernel D: fused i8 Gram GEMM + RBF epilogue, LDS-free streaming ----
// 128x128 tile, 4 independent waves (2x2, each 64x64 = 2x2 of 32-tiles).
// Fragments load straight from the tiled tb (L2-resident, XCD-swizzled tile
// order) into VGPRs; depth-2 software pipeline with named X/Y register sets;
// compiler deepens further via full unroll + its own vmcnt scheduling.
__global__ __launch_bounds__(256, 2) void mmd_gemm(const unsigned char* __restrict__ T,
                                                   const float* __restrict__ sq,
                                                   const float* __restrict__ bwp,
                                                   float* __restrict__ partials) {
  __shared__ float wred[4];

  const int tid  = threadIdx.x;
  const int lane = tid & 63;
  const int wave = tid >> 6;       // 0..3
  const int wr   = wave >> 1;      // wave row (0..1)
  const int wc   = wave & 1;       // wave col (0..1)

  // XCD-aware chunked swizzle: 8 XCDs x 260 contiguous triangular tiles
  const int tno = (blockIdx.x & 7) * 260 + (blockIdx.x >> 3);
  // triangular decode: tile tno -> (bi, bj), bi<=bj, f(bi)=bi*(129-bi)/2
  int bi = (int)((129.0f - fast_sqrt(129.0f * 129.0f - 8.0f * (float)tno)) * 0.5f);
  while (bi > 0 && bi * (129 - bi) / 2 > tno) --bi;
  while ((bi + 1) * (129 - (bi + 1)) / 2 <= tno) ++bi;
  const int bj = bi + (tno - bi * (129 - bi) / 2);

  const int col5 = lane & 31;      // row within a 32-tile
  const int hi32 = lane >> 5;      // 16-k subgroup
  const int lb   = hi32 * 256 + (lane & 15) * 16;

  // wave's fragment base pointers; tm/tn=1 adds 2 row-blocks = 32768 B;
  // k-step s adds s*512 B.
  const unsigned char* Ap = T + (size_t)(bi * 8 + wr * 4 + (col5 >> 4)) * 16384 + lb;
  const unsigned char* Bp = T + (size_t)(bj * 8 + wc * 4 + (col5 >> 4)) * 16384 + lb;

  i32x16 acc00 = {}, acc01 = {}, acc10 = {}, acc11 = {};

  // depth-2 software pipeline, named X/Y sets (no runtime-indexed arrays)
  i32x4 xa0 = LDQ(Ap, 0), xa1 = LDQ(Ap, 32768);
  i32x4 xb0 = LDQ(Bp, 0), xb1 = LDQ(Bp, 32768);
#pragma unroll
  for (int s = 0; s < 32; s += 2) {
    const int o1 = (s + 1) * 512;
    i32x4 ya0 = LDQ(Ap, o1), ya1 = LDQ(Ap, 32768 + o1);
    i32x4 yb0 = LDQ(Bp, o1), yb1 = LDQ(Bp, 32768 + o1);
    acc00 = MFI8(xa0, xb0, acc00);
    acc01 = MFI8(xa0, xb1, acc01);
    acc10 = MFI8(xa1, xb0, acc10);
    acc11 = MFI8(xa1, xb1, acc11);
    if (s + 2 < 32) {
      const int o2 = (s + 2) * 512;
      xa0 = LDQ(Ap, o2); xa1 = LDQ(Ap, 32768 + o2);
      xb0 = LDQ(Bp, o2); xb1 = LDQ(Bp, 32768 + o2);
    }
    acc00 = MFI8(ya0, yb0, acc00);
    acc01 = MFI8(ya0, yb1, acc01);
    acc10 = MFI8(ya1, yb0, acc10);
    acc11 = MFI8(ya1, yb1, acc11);
  }

  // epilogue: G = acc/QS^2 (exact int); x = l2*ni0 exp2-domain; u=2^(x/16)
  // C/D layout: col = lane&31, row = (r&3) + 8*(r>>2) + 4*(lane>>5)
  const float s16 = bwp[0] * 0.0625f;          // -log2e/(16*bw)
  const float c2i = -2.f * s16 / (QS * QS);

  const float bj0 = sq[bj * 128 + wc * 64 + col5] * s16;
  const float bj1 = sq[bj * 128 + wc * 64 + 32 + col5] * s16;

  float tsum = 0.f;
#pragma unroll
  for (int tm = 0; tm < 2; ++tm) {
    const int rbaseq = bi * 128 + wr * 64 + tm * 32 + 4 * hi32;
#pragma unroll
    for (int q = 0; q < 4; ++q) {
#pragma unroll
      for (int p = 0; p < 4; ++p) {
        const float ai = sq[rbaseq + q * 8 + p] * s16;
        const int r = q * 4 + p;
        const int v0 = tm ? acc10[r] : acc00[r];
        const int v1 = tm ? acc11[r] : acc01[r];
        tsum += EXP5(fmaf((float)v0, c2i, ai + bj0));
        tsum += EXP5(fmaf((float)v1, c2i, ai + bj1));
      }
    }
  }

#pragma unroll
  for (int off = 32; off > 0; off >>= 1) tsum += __shfl_down(tsum, off, 64);
  if (lane == 0) wred[wave] = tsum;
  __syncthreads();
  if (tid == 0) {
    float sign = ((bi < 32) == (bj < 32)) ? 1.f : -1.f;
    float wgt  = (bi == bj) ? 1.f : 2.f;
    partials[tno] = sign * wgt * ((wred[0] + wred[1]) + (wred[2] + wred[3]));
  }
}

// ---- kernel E: final reduction ----
__global__ __launch_bounds__(256) void finish_kernel(const float* __restrict__ partials,
                                                     float* __restrict__ out) {
  const int t = threadIdx.x;
  double s = 0.0;
  for (int i = t; i < NTRI; i += 256) s += (double)partials[i];
  __shared__ double rd[256];
  rd[t] = s;
  __syncthreads();
  for (int off = 128; off > 0; off >>= 1) {
    if (t < off) rd[t] += rd[t + off];
    __syncthreads();
  }
  if (t == 0) out[0] = (float)(rd[0] / 16777216.0);  // / bs^2
}

extern "C" void kernel_launch(void* const* d_in, const int* in_sizes, int n_in,
                              void* d_out, int out_size, void* d_ws, size_t ws_size,
                              hipStream_t stream) {
  const float* src = (const float*)d_in[0];
  const float* tgt = (const float*)d_in[1];
  char* ws = (char*)d_ws;
  unsigned char* tb = (unsigned char*)(ws + OFF_TB);
  float* sq       = (float*)(ws + OFF_SQ);
  float* colpart  = (float*)(ws + OFF_COLPART);
  float* colp2    = (float*)(ws + OFF_COLP2);
  float* bwp      = (float*)(ws + OFF_BWP);
  float* partials = (float*)(ws + OFF_PART);

  prep_kernel<<<dim3(512), dim3(256), 0, stream>>>(src, tgt, tb, sq, colpart);
  colred_kernel<<<dim3(8), dim3(1024), 0, stream>>>(colpart, colp2);
  bw_kernel<<<dim3(1), dim3(1024), 0, stream>>>(sq, colp2, bwp);
  mmd_gemm<<<dim3(NTRI), dim3(256), 0, stream>>>(tb, sq, bwp, partials);
  finish_kernel<<<dim3(1), dim3(256), 0, stream>>>(partials, (float*)d_out);
}

// Round 21
// 76.666 us; speedup vs baseline: 1.0817x; 1.0817x over previous
//
#include <hip/hip_runtime.h>
#include <hip/hip_bf16.h>
#include <stdint.h>
#include <stddef.h>

#define NTOT 8192
#define BS   4096
#define DIM  1024
#define NTRI 2080   // 64*65/2 triangular tiles
#define QS   20.0f  // i8 quant scale: ±127/20 = ±6.35 sigma coverage

// ws layout (bytes)
#define OFF_TB      0u          // i8, tiled layout: 8192*1024 = 8388608
#define OFF_SQ      8388608u    // f32 [8192]
#define OFF_COLPART 8421376u    // f32 [512][1024] per-16-row col partials
#define OFF_COLP2   10518528u   // f32 [8][1024]
#define OFF_BWP     10551296u   // f32 [8]
#define OFF_PART    10551360u   // f32 [NTRI]

// tb tiled layout: element (row, k) at
//   R*16384 + kt*1024 + kq*256 + r15*16 + b
// where R=row>>4, r15=row&15, kt=k>>6, kq=(k>>4)&3, b=k&15.
// GEMM ds_read_b128 for row m, 16-k group g reads (m>>4)*1024+g*256+(m&15)*16
// -> one contiguous 16B chunk; 16-lane groups read consecutive 256B:
// conflict-free (verified R14/R18: SQ_LDS_BANK_CONFLICT = 0).
// NOTE (R17): no device-scope fences/atomics — __threadfence on non-coherent
// per-XCD L2s destroyed staging locality (48.5 -> 283us).
// NOTE (R20): keep LDS staging — direct L2->VGPR streaming doubles L2 traffic
// (no intra-block dedup) and regressed 48.5 -> 58.7us.

typedef __attribute__((ext_vector_type(4)))  int   i32x4;
typedef __attribute__((ext_vector_type(16))) int   i32x16;

__device__ __forceinline__ float fast_sqrt(float x) {
#if __has_builtin(__builtin_amdgcn_sqrtf)
  return __builtin_amdgcn_sqrtf(x);
#else
  float r; asm("v_sqrt_f32 %0, %1" : "=v"(r) : "v"(x)); return r;
#endif
}

__device__ __forceinline__ float fast_exp2(float x) {
#if __has_builtin(__builtin_amdgcn_exp2f)
  return __builtin_amdgcn_exp2f(x);
#else
  float r; asm("v_exp_f32 %0, %1" : "=v"(r) : "v"(x)); return r;
#endif
}

__device__ __forceinline__ void load_lds16(const void* g, void* l) {
  __builtin_amdgcn_global_load_lds((const __attribute__((address_space(1))) void*)g,
                                   (__attribute__((address_space(3))) void*)l,
                                   16, 0, 0);
}

__device__ __forceinline__ int quant4(float4 v) {
  int q0 = __float2int_rn(fminf(fmaxf(v.x * QS, -127.f), 127.f));
  int q1 = __float2int_rn(fminf(fmaxf(v.y * QS, -127.f), 127.f));
  int q2 = __float2int_rn(fminf(fmaxf(v.z * QS, -127.f), 127.f));
  int q3 = __float2int_rn(fminf(fmaxf(v.w * QS, -127.f), 127.f));
  return (q0 & 255) | ((q1 & 255) << 8) | ((q2 & 255) << 16) | ((q3 & 255) << 24);
}

// ---- kernel A: i8 quantize into tiled layout + row sq + col partials ----
__global__ __launch_bounds__(256) void prep_kernel(const float* __restrict__ src,
                                                   const float* __restrict__ tgt,
                                                   unsigned char* __restrict__ tb,
                                                   float* __restrict__ sq,
                                                   float* __restrict__ colpart) {
  const int t = threadIdx.x;
  const int lane = t & 63, wave = t >> 6;
  const int R = blockIdx.x;        // 16-row block
  const int r0 = R * 16;
  const int kt = t >> 4, kq = (t >> 2) & 3, b0 = (t & 3) * 4;
  unsigned char* dstbase = tb + (size_t)R * 16384 + kt * 1024 + kq * 256 + b0;
  __shared__ float rs[16][4];
  float c0 = 0.f, c1 = 0.f, c2 = 0.f, c3 = 0.f;
#pragma unroll 4
  for (int r = 0; r < 16; ++r) {
    const int row = r0 + r;
    const float* base = (row < BS) ? (src + (size_t)row * DIM)
                                   : (tgt + (size_t)(row - BS) * DIM);
    float4 v = *reinterpret_cast<const float4*>(base + t * 4);
    *reinterpret_cast<int*>(dstbase + r * 16) = quant4(v);   // r15 = r
    c0 += v.x; c1 += v.y; c2 += v.z; c3 += v.w;
    float s = v.x*v.x + v.y*v.y + v.z*v.z + v.w*v.w;
#pragma unroll
    for (int off = 32; off > 0; off >>= 1) s += __shfl_down(s, off, 64);
    if (lane == 0) rs[r][wave] = s;
  }
  float4 cp = {c0, c1, c2, c3};
  *reinterpret_cast<float4*>(colpart + (size_t)R * 1024 + t * 4) = cp;
  __syncthreads();
  if (t < 16) sq[r0 + t] = (rs[t][0] + rs[t][1]) + (rs[t][2] + rs[t][3]);
}

// ---- kernel B: reduce 512 col-partial groups -> 8 ----
__global__ __launch_bounds__(1024) void colred_kernel(const float* __restrict__ colpart,
                                                      float* __restrict__ colp2) {
  const int b = blockIdx.x, t = threadIdx.x;   // 8 blocks x 1024 cols
  float s = 0.f;
  for (int g = b * 64; g < b * 64 + 64; ++g) s += colpart[(size_t)g * 1024 + t];
  colp2[b * 1024 + t] = s;
}

// ---- kernel C: bandwidth from analytic sum(L2) ----
__global__ __launch_bounds__(1024) void bw_kernel(const float* __restrict__ sq,
                                                  const float* __restrict__ colp2,
                                                  float* __restrict__ bwp) {
  const int t = threadIdx.x;
  double s1 = 0.0;
#pragma unroll
  for (int i = 0; i < 8; ++i) s1 += (double)sq[t + i * 1024];
  float s = 0.f;
#pragma unroll
  for (int j = 0; j < 8; ++j) s += colp2[j * 1024 + t];
  double s2 = (double)s * (double)s;
  __shared__ double r1[1024], r2[1024];
  r1[t] = s1; r2[t] = s2;
  __syncthreads();
  for (int off = 512; off > 0; off >>= 1) {
    if (t < off) { r1[t] += r1[t + off]; r2[t] += r2[t + off]; }
    __syncthreads();
  }
  if (t == 0) {
    const double n = (double)NTOT;
    double sumL2 = 2.0 * n * r1[0] - 2.0 * r2[0];
    double bw = sumL2 / (n * n - n);
    bw = bw / 4.0;  // KERNEL_MUL^(KERNEL_NUM//2) = 2^2
    const double LOG2E = 1.4426950408889634;
    for (int k = 0; k < 5; ++k)
      bwp[k] = (float)(-LOG2E / (bw * (double)(1 << k)));  // exp2-folded
  }
}

// stage one K=64 tile pair (A,B): 8KB each = 512 linear 16B chunks, 4/thread.
#define STAGE(kt1024, ldsA, ldsB)                                             \
  do {                                                                        \
    load_lds16(T + a0g + (kt1024), (ldsA) + (size_t)(wave * 64) * 16);        \
    load_lds16(T + a1g + (kt1024), (ldsA) + (size_t)(256 + wave * 64) * 16);  \
    load_lds16(T + b0g + (kt1024), (ldsB) + (size_t)(wave * 64) * 16);        \
    load_lds16(T + b1g + (kt1024), (ldsB) + (size_t)(256 + wave * 64) * 16);  \
  } while (0)

// one K=64 step: 2 k-halves x (4 ds_read_b128 + 4 MFMA 32x32x32_i8).
#define COMPUTE64(Abuf, Bbuf)                                                 \
  do {                                                                        \
    _Pragma("unroll")                                                         \
    for (int kk = 0; kk < 2; ++kk) {                                          \
      i32x4 fa0 = *reinterpret_cast<const i32x4*>(&(Abuf)[abase + kk * 512]); \
      i32x4 fa1 = *reinterpret_cast<const i32x4*>(&(Abuf)[abase + 2048 + kk * 512]); \
      i32x4 fb0 = *reinterpret_cast<const i32x4*>(&(Bbuf)[bbase + kk * 512]); \
      i32x4 fb1 = *reinterpret_cast<const i32x4*>(&(Bbuf)[bbase + 2048 + kk * 512]); \
      acc00 = __builtin_amdgcn_mfma_i32_32x32x32_i8(fa0, fb0, acc00, 0, 0, 0); \
      acc01 = __builtin_amdgcn_mfma_i32_32x32x32_i8(fa0, fb1, acc01, 0, 0, 0); \
      acc10 = __builtin_amdgcn_mfma_i32_32x32x32_i8(fa1, fb0, acc10, 0, 0, 0); \
      acc11 = __builtin_amdgcn_mfma_i32_32x32x32_i8(fa1, fb1, acc11, 0, 0, 0); \
    }                                                                         \
  } while (0)

#define BARR __builtin_amdgcn_s_barrier()

#define EXP5(x16) ({ float u_ = fast_exp2(x16);                               \
                     float u2_ = u_ * u_, u4_ = u2_ * u2_;                    \
                     float u8_ = u4_ * u4_, u16_ = u8_ * u8_;                 \
                     ((u_ + u2_) + (u4_ + u8_)) + u16_; })

// ---- kernel D: fused i8 Gram GEMM + RBF epilogue, upper-triangular tiles ----
// 128x128 tile, BK=64 i8, 4 waves (2x2, each 64x64 out), proven R14 config:
// 32KB LDS -> 4 blocks/CU TLP + counted-vmcnt dbuf (never drain-0 in loop).
__global__ __launch_bounds__(256, 4) void mmd_gemm(const unsigned char* __restrict__ T,
                                                   const float* __restrict__ sq,
                                                   const float* __restrict__ bwp,
                                                   float* __restrict__ partials) {
  __shared__ __align__(16) unsigned char sA0[8192], sA1[8192];
  __shared__ __align__(16) unsigned char sB0[8192], sB1[8192];
  __shared__ float wred[4];

  const int tid  = threadIdx.x;
  const int lane = tid & 63;
  const int wave = tid >> 6;       // 0..3
  const int wr   = wave >> 1;      // wave row (0..1)
  const int wc   = wave & 1;       // wave col (0..1)

  // XCD-aware chunked swizzle: 8 XCDs x 260 contiguous triangular tiles
  const int tno = (blockIdx.x & 7) * 260 + (blockIdx.x >> 3);
  // triangular decode: tile tno -> (bi, bj), bi<=bj, f(bi)=bi*(129-bi)/2
  int bi = (int)((129.0f - fast_sqrt(129.0f * 129.0f - 8.0f * (float)tno)) * 0.5f);
  while (bi > 0 && bi * (129 - bi) / 2 > tno) --bi;
  while ((bi + 1) * (129 - (bi + 1)) / 2 <= tno) ++bi;
  const int bj = bi + (tno - bi * (129 - bi) / 2);

  // row-block bases (8 x 16-row blocks per 128-row tile)
  const int aRB = bi * 8, bRB = bj * 8;

  // staging source offsets: chunk f -> row-block f>>6, 16B chunk f&63
  const int f0 = tid, f1 = 256 + tid;
  const size_t a0g = (size_t)(aRB + (f0 >> 6)) * 16384 + (f0 & 63) * 16;
  const size_t a1g = (size_t)(aRB + (f1 >> 6)) * 16384 + (f1 & 63) * 16;
  const size_t b0g = (size_t)(bRB + (f0 >> 6)) * 16384 + (f0 & 63) * 16;
  const size_t b1g = (size_t)(bRB + (f1 >> 6)) * 16384 + (f1 & 63) * 16;

  i32x16 acc00 = {}, acc01 = {}, acc10 = {}, acc11 = {};

  const int col5 = lane & 31;      // m/n within a 32-tile
  const int hi32 = lane >> 5;      // 16-k subgroup
  const int abase0 = (col5 >> 4) * 1024 + hi32 * 256 + (lane & 15) * 16;
  const int abase = wr * 4096 + abase0;
  const int bbase = wc * 4096 + abase0;

  // prologue: stage K-tile 0 into buf0 (4 loads in flight)
  STAGE(0, sA0, sB0);

  for (int t = 0; t < 8; ++t) {
    // even tile 2t in buf0; stage odd tile 2t+1 into buf1
    STAGE((2 * t + 1) * 1024, sA1, sB1);
    asm volatile("s_waitcnt vmcnt(4)" ::: "memory");   // tile-2t loads landed
    BARR;
    __builtin_amdgcn_sched_barrier(0);
    COMPUTE64(sA0, sB0);
    __builtin_amdgcn_sched_barrier(0);
    BARR;                                              // buf0 reads done

    // odd tile 2t+1 in buf1; stage even tile 2t+2 into buf0
    if (t < 7) {
      STAGE((2 * t + 2) * 1024, sA0, sB0);
      asm volatile("s_waitcnt vmcnt(4)" ::: "memory");
    } else {
      asm volatile("s_waitcnt vmcnt(0)" ::: "memory");
    }
    BARR;
    __builtin_amdgcn_sched_barrier(0);
    COMPUTE64(sA1, sB1);
    __builtin_amdgcn_sched_barrier(0);
    BARR;                                              // buf1 reads done
  }

  // epilogue: G = acc/QS^2 (exact int); x = l2*ni0 exp2-domain; u=2^(x/16)
  // C/D layout: col = lane&31, row = (r&3) + 8*(r>>2) + 4*(lane>>5)
  const float s16 = bwp[0] * 0.0625f;          // -log2e/(16*bw)
  const float c2i = -2.f * s16 / (QS * QS);

  const float bj0 = sq[bj * 128 + wc * 64 + col5] * s16;
  const float bj1 = sq[bj * 128 + wc * 64 + 32 + col5] * s16;

  float tsum = 0.f;
#pragma unroll
  for (int tm = 0; tm < 2; ++tm) {
    const int rbaseq = bi * 128 + wr * 64 + tm * 32 + 4 * hi32;
#pragma unroll
    for (int q = 0; q < 4; ++q) {
#pragma unroll
      for (int p = 0; p < 4; ++p) {
        const float ai = sq[rbaseq + q * 8 + p] * s16;
        const int r = q * 4 + p;
        const int v0 = tm ? acc10[r] : acc00[r];
        const int v1 = tm ? acc11[r] : acc01[r];
        tsum += EXP5(fmaf((float)v0, c2i, ai + bj0));
        tsum += EXP5(fmaf((float)v1, c2i, ai + bj1));
      }
    }
  }

#pragma unroll
  for (int off = 32; off > 0; off >>= 1) tsum += __shfl_down(tsum, off, 64);
  if (lane == 0) wred[wave] = tsum;
  __syncthreads();
  if (tid == 0) {
    float sign = ((bi < 32) == (bj < 32)) ? 1.f : -1.f;
    float wgt  = (bi == bj) ? 1.f : 2.f;
    partials[tno] = sign * wgt * ((wred[0] + wred[1]) + (wred[2] + wred[3]));
  }
}

// ---- kernel E: final reduction ----
__global__ __launch_bounds__(256) void finish_kernel(const float* __restrict__ partials,
                                                     float* __restrict__ out) {
  const int t = threadIdx.x;
  double s = 0.0;
  for (int i = t; i < NTRI; i += 256) s += (double)partials[i];
  __shared__ double rd[256];
  rd[t] = s;
  __syncthreads();
  for (int off = 128; off > 0; off >>= 1) {
    if (t < off) rd[t] += rd[t + off];
    __syncthreads();
  }
  if (t == 0) out[0] = (float)(rd[0] / 16777216.0);  // / bs^2
}

extern "C" void kernel_launch(void* const* d_in, const int* in_sizes, int n_in,
                              void* d_out, int out_size, void* d_ws, size_t ws_size,
                              hipStream_t stream) {
  const float* src = (const float*)d_in[0];
  const float* tgt = (const float*)d_in[1];
  char* ws = (char*)d_ws;
  unsigned char* tb = (unsigned char*)(ws + OFF_TB);
  float* sq       = (float*)(ws + OFF_SQ);
  float* colpart  = (float*)(ws + OFF_COLPART);
  float* colp2    = (float*)(ws + OFF_COLP2);
  float* bwp      = (float*)(ws + OFF_BWP);
  float* partials = (float*)(ws + OFF_PART);

  prep_kernel<<<dim3(512), dim3(256), 0, stream>>>(src, tgt, tb, sq, colpart);
  colred_kernel<<<dim3(8), dim3(1024), 0, stream>>>(colpart, colp2);
  bw_kernel<<<dim3(1), dim3(1024), 0, stream>>>(sq, colp2, bwp);
  mmd_gemm<<<dim3(NTRI), dim3(256), 0, stream>>>(tb, sq, bwp, partials);
  finish_kernel<<<dim3(1), dim3(256), 0, stream>>>(partials, (float*)d_out);
}